// Round 2
// baseline (4411.238 us; speedup 1.0000x reference)
//
#include <hip/hip_runtime.h>

#define NROWS 262144
#define EPSV 1e-5f

// ws float offsets
#define WT4_OFF   0        // 4096 floats: lin4_wT[i][o]
#define SUMS_OFF  4096     // 262 floats: s1[131], s2[131]
#define SCALE_OFF 4608     // 131 floats
#define SHIFT_OFF 4864     // 131 floats

__global__ __launch_bounds__(256) void k_prep(const float* __restrict__ lin4_w,
                                              float* __restrict__ wT)
{
    int idx = blockIdx.x * 256 + threadIdx.x;   // 0..4095
    int o = idx & 63, i = idx >> 6;
    wT[i * 64 + o] = lin4_w[o * 64 + i];
}

__global__ __launch_bounds__(256) void k_stats(const float* __restrict__ sums,
                                               const float* __restrict__ bn_g,
                                               const float* __restrict__ bn_b,
                                               float* __restrict__ scale,
                                               float* __restrict__ shift)
{
    int j = threadIdx.x;
    if (j < 131) {
        const float inv = 1.0f / (float)NROWS;
        float mean = sums[j] * inv;
        float var  = sums[131 + j] * inv - mean * mean;
        var = fmaxf(var, 0.0f);
        float sc = bn_g[j] * rsqrtf(var + EPSV);
        scale[j] = sc;
        shift[j] = bn_b[j] - mean * sc;
    }
}

// Pass A: per-row MLP + RBF -> x(131) in regs -> h = x@W1^T + b1 -> d_out (row-major)
// plus per-column sum / sumsq accumulation for BN.
// launch_bounds(256,1): allow ~512 VGPRs so v[64]+z[64] live set never spills.
__global__ __launch_bounds__(256, 1) void k_A(
    const float* __restrict__ corner, const float* __restrict__ normal,
    const float* __restrict__ conv_w, const float* __restrict__ conv_b,
    const float* __restrict__ lin3_w, const float* __restrict__ lin3_b,
    const float* __restrict__ lin4_wT, const float* __restrict__ lin4_b,
    const float* __restrict__ kern,
    const float* __restrict__ w1, const float* __restrict__ b1,
    float* __restrict__ h_out, float* __restrict__ sums)
{
    const int tid  = threadIdx.x;
    const int wave = tid >> 6, lane = tid & 63;
    const int row  = blockIdx.x * 256 + tid;
    const int row0 = blockIdx.x * 256 + wave * 64;

    // ---- inputs ----
    float cr[9];
    #pragma unroll
    for (int k = 0; k < 9; k++) cr[k] = corner[row * 9 + k];
    const float nr0 = normal[row * 3 + 0];
    const float nr1 = normal[row * 3 + 1];
    const float nr2 = normal[row * 3 + 2];

    // mean over the 3 pair-rows collapses (linearity): m = (c1+c2+c3)/3
    const float m0 = (cr[0] + cr[3] + cr[6]) * (1.0f / 3.0f);
    const float m1 = (cr[1] + cr[4] + cr[7]) * (1.0f / 3.0f);
    const float m2 = (cr[2] + cr[5] + cr[8]) * (1.0f / 3.0f);

    // ---- a[32] = m @ (conv_w[:, :3]+conv_w[:, 3:])^T + conv_b ----
    float a[32];
    #pragma unroll
    for (int o = 0; o < 32; o++) {
        const float* w = conv_w + o * 6;
        a[o] = conv_b[o] + m0 * (w[0] + w[3]) + m1 * (w[1] + w[4]) + m2 * (w[2] + w[5]);
    }

    // ---- v[64] = relu(a@lin3^T + b3) @ lin4^T + b4, streamed over hidden idx ----
    float v[64];
    #pragma unroll
    for (int o = 0; o < 64; o++) v[o] = lin4_b[o];
    #pragma unroll 1
    for (int i3 = 0; i3 < 64; i3++) {
        float t0 = lin3_b[i3], t1 = 0.0f;
        const float* w = lin3_w + i3 * 32;
        #pragma unroll
        for (int i = 0; i < 32; i += 2) { t0 += a[i] * w[i]; t1 += a[i + 1] * w[i + 1]; }
        float t = fmaxf(t0 + t1, 0.0f);
        const float* wt = lin4_wT + i3 * 64;
        #pragma unroll
        for (int o = 0; o < 64; o++) v[o] += t * wt[o];
    }

    // ---- z[64]: RBF over 64x4 kernel points ----
    float z[64];
    #pragma unroll
    for (int mi = 0; mi < 64; mi++) {
        float acc = 0.0f;
        #pragma unroll
        for (int l = 0; l < 4; l++) {
            const float* kp = kern + (mi * 4 + l) * 3;
            float d0 = nr0 - kp[0], d1 = nr1 - kp[1], d2 = nr2 - kp[2];
            acc += __expf(-(d0 * d0 + d1 * d1 + d2 * d2));
        }
        z[mi] = acc * 0.03125f;   // 0.5 / (K*4) = 1/32
    }

    // ---- conv1: h_j = b1[j] + x . W1[j,:], x = [normal(3), v(64), z(64)] ----
    __shared__ float lds[4][16][68];
    #pragma unroll
    for (int jb = 0; jb < 131; jb += 16) {
        const int jcnt = (jb + 16 <= 131) ? 16 : (131 - jb);
        #pragma unroll 1
        for (int jj = 0; jj < jcnt; jj++) {
            const int j = jb + jj;
            const float* w = w1 + j * 131;
            float acc0 = b1[j] + nr0 * w[0] + nr1 * w[1] + nr2 * w[2];
            float acc1 = 0.0f, acc2 = 0.0f, acc3 = 0.0f;
            #pragma unroll
            for (int i = 0; i < 64; i += 4) {
                acc0 += v[i]     * w[3 + i];
                acc1 += v[i + 1] * w[4 + i];
                acc2 += v[i + 2] * w[5 + i];
                acc3 += v[i + 3] * w[6 + i];
            }
            #pragma unroll
            for (int i = 0; i < 64; i += 4) {
                acc0 += z[i]     * w[67 + i];
                acc1 += z[i + 1] * w[68 + i];
                acc2 += z[i + 2] * w[69 + i];
                acc3 += z[i + 3] * w[70 + i];
            }
            float acc = (acc0 + acc1) + (acc2 + acc3);
            // BN stats: wave-reduce then one atomic per wave
            float s1 = acc, s2 = acc * acc;
            #pragma unroll
            for (int off = 32; off > 0; off >>= 1) {
                s1 += __shfl_xor(s1, off);
                s2 += __shfl_xor(s2, off);
            }
            if (lane == 0) {
                atomicAdd(&sums[j], s1);
                atomicAdd(&sums[131 + j], s2);
            }
            lds[wave][jj][lane] = acc;
        }
        __syncthreads();
        // coalesced flush: (r,c) -> h_out[(row0+r)*131 + jb + c]
        #pragma unroll 1
        for (int k = 0; k < jcnt; k++) {
            int flat = k * 64 + lane;
            int r = flat / jcnt;          // constant jcnt after unroll of jb
            int c = flat - r * jcnt;
            h_out[(row0 + r) * 131 + jb + c] = lds[wave][c][r];
        }
        __syncthreads();
    }
}

// Pass B: in-place on d_out: read h rows (staged/coalesced), BN+relu, conv2, write out.
__global__ __launch_bounds__(256, 1) void k_B(
    const float* h_in, const float* __restrict__ scale,
    const float* __restrict__ shift,
    const float* __restrict__ w2, const float* __restrict__ b2,
    float* out)
{
    const int tid  = threadIdx.x;
    const int wave = tid >> 6, lane = tid & 63;
    const int row0 = blockIdx.x * 256 + wave * 64;
    __shared__ float lds[4][16][68];

    float hn[131];
    // ---- staged coalesced read of this wave's 64 rows + BN + relu ----
    #pragma unroll
    for (int jb = 0; jb < 131; jb += 16) {
        const int jcnt = (jb + 16 <= 131) ? 16 : (131 - jb);
        #pragma unroll 1
        for (int k = 0; k < jcnt; k++) {
            int flat = k * 64 + lane;
            int r = flat / jcnt;
            int c = flat - r * jcnt;
            lds[wave][c][r] = h_in[(row0 + r) * 131 + jb + c];
        }
        __syncthreads();
        #pragma unroll
        for (int c = 0; c < 16; c++) {
            if (c < jcnt)
                hn[jb + c] = fmaxf(lds[wave][c][lane] * scale[jb + c] + shift[jb + c], 0.0f);
        }
        __syncthreads();
    }

    // ---- conv2 + staged coalesced write (in-place safe: all reads done above) ----
    #pragma unroll
    for (int ob = 0; ob < 131; ob += 16) {
        const int ocnt = (ob + 16 <= 131) ? 16 : (131 - ob);
        #pragma unroll 1
        for (int oo = 0; oo < ocnt; oo++) {
            const int o = ob + oo;
            const float* w = w2 + o * 131;
            float a0 = b2[o], a1 = 0.0f, a2 = 0.0f, a3 = 0.0f;
            #pragma unroll
            for (int i = 0; i < 128; i += 4) {
                a0 += hn[i]     * w[i];
                a1 += hn[i + 1] * w[i + 1];
                a2 += hn[i + 2] * w[i + 2];
                a3 += hn[i + 3] * w[i + 3];
            }
            a0 += hn[128] * w[128];
            a1 += hn[129] * w[129];
            a2 += hn[130] * w[130];
            lds[wave][oo][lane] = (a0 + a1) + (a2 + a3);
        }
        __syncthreads();
        #pragma unroll 1
        for (int k = 0; k < ocnt; k++) {
            int flat = k * 64 + lane;
            int r = flat / ocnt;
            int c = flat - r * ocnt;
            out[(row0 + r) * 131 + ob + c] = lds[wave][c][r];
        }
        __syncthreads();
    }
}

extern "C" void kernel_launch(void* const* d_in, const int* in_sizes, int n_in,
                              void* d_out, int out_size, void* d_ws, size_t ws_size,
                              hipStream_t stream) {
    (void)in_sizes; (void)n_in; (void)out_size; (void)ws_size;
    const float* corner = (const float*)d_in[0];
    const float* normal = (const float*)d_in[1];
    // d_in[2] = neighbour (unused by reference)
    const float* conv_w = (const float*)d_in[3];
    const float* conv_b = (const float*)d_in[4];
    const float* lin3_w = (const float*)d_in[5];
    const float* lin3_b = (const float*)d_in[6];
    const float* lin4_w = (const float*)d_in[7];
    const float* lin4_b = (const float*)d_in[8];
    const float* kern   = (const float*)d_in[9];
    const float* w1     = (const float*)d_in[10];
    const float* b1     = (const float*)d_in[11];
    const float* bn_g   = (const float*)d_in[12];
    const float* bn_b   = (const float*)d_in[13];
    const float* w2     = (const float*)d_in[14];
    const float* b2     = (const float*)d_in[15];
    float* out = (float*)d_out;
    float* ws  = (float*)d_ws;

    hipMemsetAsync(ws + SUMS_OFF, 0, 262 * sizeof(float), stream);
    k_prep<<<16, 256, 0, stream>>>(lin4_w, ws + WT4_OFF);
    k_A<<<NROWS / 256, 256, 0, stream>>>(corner, normal, conv_w, conv_b,
                                         lin3_w, lin3_b, ws + WT4_OFF, lin4_b,
                                         kern, w1, b1, out, ws + SUMS_OFF);
    k_stats<<<1, 256, 0, stream>>>(ws + SUMS_OFF, bn_g, bn_b,
                                   ws + SCALE_OFF, ws + SHIFT_OFF);
    k_B<<<NROWS / 256, 256, 0, stream>>>(out, ws + SCALE_OFF, ws + SHIFT_OFF,
                                         w2, b2, out);
}

// Round 3
// 370.194 us; speedup vs baseline: 11.9160x; 11.9160x over previous
//
#include <hip/hip_runtime.h>

#define NROWS 262144
#define NBLK  1024          // NROWS/256
#define PLANE_B   8388608ull   // NROWS*32 bytes per 16-col bf16 plane
#define PLANE_US  4194304ull   // ushorts per plane

typedef short  short8 __attribute__((ext_vector_type(8)));
typedef float  f32x4  __attribute__((ext_vector_type(4)));

static __device__ __forceinline__ unsigned short f2bf(float f) {
    unsigned u = __float_as_uint(f);
    u = u + 0x7fffu + ((u >> 16) & 1u);   // RNE
    return (unsigned short)(u >> 16);
}
static __device__ __forceinline__ float bf2f(unsigned short h) {
    return __uint_as_float(((unsigned)h) << 16);
}

// ------------------------------------------------------------------
// k_A1: per-row MLP front end. thread = row.
//   a[32] -> t stream -> T_lds(bf16) ; v = T @ lin4^T via MFMA
//   writes v planes 0..3 and z planes 4..7 (bf16, chunked-col-major) into X
// ------------------------------------------------------------------
__global__ __launch_bounds__(256) void k_A1(
    const float* __restrict__ corner, const float* __restrict__ normal,
    const float* __restrict__ conv_w, const float* __restrict__ conv_b,
    const float* __restrict__ lin3_w, const float* __restrict__ lin3_b,
    const float* __restrict__ lin4_w, const float* __restrict__ lin4_b,
    const float* __restrict__ kern,
    unsigned short* __restrict__ X)
{
    __shared__ unsigned short T[4 * 64 * 72];
    __shared__ unsigned short B1[64 * 72];
    __shared__ unsigned short mini[4 * 64 * 20];

    const int tid  = threadIdx.x;
    const int wave = tid >> 6, lane = tid & 63;
    const int kg   = lane >> 4, c15 = lane & 15;
    const int row  = blockIdx.x * 256 + tid;

    // stage B1 = lin4_w as [o][i3] bf16 (N-major, K contiguous)
    for (int idx = tid; idx < 4096; idx += 256) {
        int o = idx >> 6, i3 = idx & 63;
        B1[o * 72 + i3] = f2bf(lin4_w[idx]);
    }

    // ---- inputs ----
    float cr[9];
    #pragma unroll
    for (int k = 0; k < 9; k++) cr[k] = corner[row * 9 + k];
    const float nr0 = normal[row * 3 + 0];
    const float nr1 = normal[row * 3 + 1];
    const float nr2 = normal[row * 3 + 2];
    const float m0 = (cr[0] + cr[3] + cr[6]) * (1.0f / 3.0f);
    const float m1 = (cr[1] + cr[4] + cr[7]) * (1.0f / 3.0f);
    const float m2 = (cr[2] + cr[5] + cr[8]) * (1.0f / 3.0f);

    float a[32];
    #pragma unroll
    for (int o = 0; o < 32; o++) {
        const float* w = conv_w + o * 6;
        a[o] = conv_b[o] + m0 * (w[0] + w[3]) + m1 * (w[1] + w[4]) + m2 * (w[2] + w[5]);
    }

    // ---- t stream into T_lds (bf16) ----
    #pragma unroll 2
    for (int i3 = 0; i3 < 64; i3++) {
        const float* w = lin3_w + i3 * 32;
        float t0 = lin3_b[i3], t1 = 0.0f;
        #pragma unroll
        for (int i = 0; i < 32; i += 2) { t0 += a[i] * w[i]; t1 += a[i + 1] * w[i + 1]; }
        float t = fmaxf(t0 + t1, 0.0f);
        T[(wave * 64 + lane) * 72 + i3] = f2bf(t);
    }

    // ---- z: 4 planes of 16 cols each, direct coalesced bf16 stores ----
    #pragma unroll 1
    for (int cz = 0; cz < 4; cz++) {
        unsigned pk[8];
        #pragma unroll
        for (int q = 0; q < 8; q++) {
            float zz[2];
            #pragma unroll
            for (int h = 0; h < 2; h++) {
                int mi = cz * 16 + q * 2 + h;
                float acc = 0.0f;
                #pragma unroll
                for (int l = 0; l < 4; l++) {
                    const float* kp = kern + (mi * 4 + l) * 3;
                    float d0 = nr0 - kp[0], d1 = nr1 - kp[1], d2 = nr2 - kp[2];
                    acc += __expf(-(d0 * d0 + d1 * d1 + d2 * d2));
                }
                zz[h] = acc * 0.03125f;
            }
            pk[q] = (unsigned)f2bf(zz[0]) | ((unsigned)f2bf(zz[1]) << 16);
        }
        uint4* dst = (uint4*)((char*)X + (4 + cz) * PLANE_B + (size_t)row * 32);
        dst[0] = make_uint4(pk[0], pk[1], pk[2], pk[3]);
        dst[1] = make_uint4(pk[4], pk[5], pk[6], pk[7]);
    }

    __syncthreads();

    // ---- G1: V(64rows x 64) = T @ lin4^T + b4, per wave ----
    #pragma unroll 1
    for (int n = 0; n < 4; n++) {
        short8 bf0 = *(const short8*)&B1[(n * 16 + c15) * 72 + kg * 8];
        short8 bf1 = *(const short8*)&B1[(n * 16 + c15) * 72 + 32 + kg * 8];
        float bias = lin4_b[n * 16 + c15];
        #pragma unroll
        for (int m = 0; m < 4; m++) {
            f32x4 acc = {bias, bias, bias, bias};
            short8 a0 = *(const short8*)&T[(wave * 64 + m * 16 + c15) * 72 + kg * 8];
            short8 a1 = *(const short8*)&T[(wave * 64 + m * 16 + c15) * 72 + 32 + kg * 8];
            acc = __builtin_amdgcn_mfma_f32_16x16x32_bf16(a0, bf0, acc, 0, 0, 0);
            acc = __builtin_amdgcn_mfma_f32_16x16x32_bf16(a1, bf1, acc, 0, 0, 0);
            #pragma unroll
            for (int r = 0; r < 4; r++)
                mini[(wave * 64 + m * 16 + kg * 4 + r) * 20 + c15] = f2bf(acc[r]);
        }
        asm volatile("s_waitcnt lgkmcnt(0)" ::: "memory");
        const uint2* q = (const uint2*)&mini[(wave * 64 + lane) * 20];
        uint2 q0 = q[0], q1 = q[1], q2 = q[2], q3 = q[3];
        uint4* dst = (uint4*)((char*)X + (size_t)n * PLANE_B +
                              (size_t)(blockIdx.x * 256 + wave * 64 + lane) * 32);
        dst[0] = make_uint4(q0.x, q0.y, q1.x, q1.y);
        dst[1] = make_uint4(q2.x, q2.y, q3.x, q3.y);
    }
}

// ------------------------------------------------------------------
// k_A2: H = X @ W1^T + b1 (K permuted: [v64 | z64 | normal3]),
//       BN column partials -> LDS -> 64-slot spread atomics.
// ------------------------------------------------------------------
__global__ __launch_bounds__(256) void k_A2(
    const unsigned short* __restrict__ X, const float* __restrict__ normal,
    const float* __restrict__ w1, const float* __restrict__ b1,
    unsigned short* __restrict__ H, float* __restrict__ sums)
{
    __shared__ unsigned short Bs[144 * 168];
    __shared__ unsigned short mini[4 * 32 * 20];
    __shared__ float sl[288];

    const int tid  = threadIdx.x;
    const int wave = tid >> 6, lane = tid & 63;
    const int kg   = lane >> 4, c15 = lane & 15;

    for (int i = tid; i < 12096; i += 256) ((unsigned*)Bs)[i] = 0u;
    for (int i = tid; i < 288; i += 256) sl[i] = 0.0f;
    __syncthreads();
    for (int idx = tid; idx < 17161; idx += 256) {
        unsigned n = (unsigned)idx / 131u, ks = (unsigned)idx - n * 131u;
        unsigned kp = ks < 3 ? 128 + ks : ks - 3;
        Bs[n * 168 + kp] = f2bf(w1[idx]);
    }
    __syncthreads();

    const int rwave = blockIdx.x * 256 + wave * 64;

    #pragma unroll 1
    for (int mp = 0; mp < 2; mp++) {
        short8 af[2][5];
        #pragma unroll
        for (int mi = 0; mi < 2; mi++) {
            int arow = rwave + mp * 32 + mi * 16 + c15;
            #pragma unroll
            for (int ks = 0; ks < 4; ks++) {
                int p = ks * 2 + (kg >> 1);
                af[mi][ks] = *(const short8*)(X + (size_t)p * PLANE_US +
                                              (size_t)arow * 16 + (kg & 1) * 8);
            }
            short8 a4 = {0, 0, 0, 0, 0, 0, 0, 0};
            if (kg == 0) {
                a4[0] = (short)f2bf(normal[arow * 3 + 0]);
                a4[1] = (short)f2bf(normal[arow * 3 + 1]);
                a4[2] = (short)f2bf(normal[arow * 3 + 2]);
            }
            af[mi][4] = a4;
        }
        #pragma unroll 1
        for (int n = 0; n < 9; n++) {
            int col = n * 16 + c15;
            float bias = (col < 131) ? b1[col] : 0.0f;
            short8 bf[5];
            #pragma unroll
            for (int ks = 0; ks < 5; ks++)
                bf[ks] = *(const short8*)&Bs[(unsigned)(n * 16 + c15) * 168 + ks * 32 + kg * 8];
            f32x4 acc0 = {bias, bias, bias, bias};
            f32x4 acc1 = {bias, bias, bias, bias};
            #pragma unroll
            for (int ks = 0; ks < 5; ks++) {
                acc0 = __builtin_amdgcn_mfma_f32_16x16x32_bf16(af[0][ks], bf[ks], acc0, 0, 0, 0);
                acc1 = __builtin_amdgcn_mfma_f32_16x16x32_bf16(af[1][ks], bf[ks], acc1, 0, 0, 0);
            }
            // BN partials (fp32, exact)
            float s1 = acc0[0] + acc0[1] + acc0[2] + acc0[3]
                     + acc1[0] + acc1[1] + acc1[2] + acc1[3];
            float s2 = acc0[0]*acc0[0] + acc0[1]*acc0[1] + acc0[2]*acc0[2] + acc0[3]*acc0[3]
                     + acc1[0]*acc1[0] + acc1[1]*acc1[1] + acc1[2]*acc1[2] + acc1[3]*acc1[3];
            s1 += __shfl_xor(s1, 16); s2 += __shfl_xor(s2, 16);
            s1 += __shfl_xor(s1, 32); s2 += __shfl_xor(s2, 32);
            if (lane < 16) { atomicAdd(&sl[col], s1); atomicAdd(&sl[144 + col], s2); }
            // H flush via per-wave mini transpose (bf16, 32B/row chunks)
            #pragma unroll
            for (int r = 0; r < 4; r++) {
                mini[(wave * 32 + kg * 4 + r) * 20 + c15]      = f2bf(acc0[r]);
                mini[(wave * 32 + 16 + kg * 4 + r) * 20 + c15] = f2bf(acc1[r]);
            }
            asm volatile("s_waitcnt lgkmcnt(0)" ::: "memory");
            if (lane < 32) {
                const uint2* q = (const uint2*)&mini[(wave * 32 + lane) * 20];
                uint2 q0 = q[0], q1 = q[1], q2 = q[2], q3 = q[3];
                uint4* dst = (uint4*)((char*)H + (size_t)n * PLANE_B +
                                      (size_t)(rwave + mp * 32 + lane) * 32);
                dst[0] = make_uint4(q0.x, q0.y, q1.x, q1.y);
                dst[1] = make_uint4(q2.x, q2.y, q3.x, q3.y);
            }
        }
    }
    __syncthreads();
    if (tid < 144) {
        float* dst = sums + (blockIdx.x & 63) * 288;
        atomicAdd(&dst[tid], sl[tid]);
        atomicAdd(&dst[144 + tid], sl[144 + tid]);
    }
}

// ------------------------------------------------------------------
__global__ void k_stats(const float* __restrict__ sums,
                        const float* __restrict__ bn_g, const float* __restrict__ bn_b,
                        float* __restrict__ scalep, float* __restrict__ shiftp)
{
    int j = threadIdx.x;
    if (j < 160) {
        float sc = 0.0f, sh = 0.0f;
        if (j < 131) {
            float s1 = 0.0f, s2 = 0.0f;
            #pragma unroll 4
            for (int s = 0; s < 64; s++) {
                s1 += sums[s * 288 + j];
                s2 += sums[s * 288 + 144 + j];
            }
            const float inv = 1.0f / (float)NROWS;
            float mean = s1 * inv;
            float var = fmaxf(s2 * inv - mean * mean, 0.0f);
            sc = bn_g[j] * rsqrtf(var + 1e-5f);
            sh = bn_b[j] - mean * sc;
        }
        scalep[j] = sc; shiftp[j] = sh;
    }
}

// ------------------------------------------------------------------
// k_B: out = relu(scale*H + shift) @ W2^T + b2  (fp32 out, direct stores)
// ------------------------------------------------------------------
__global__ __launch_bounds__(256) void k_B(
    const unsigned short* __restrict__ H, const float* __restrict__ scalep,
    const float* __restrict__ shiftp, const float* __restrict__ w2,
    const float* __restrict__ b2, float* __restrict__ out)
{
    __shared__ unsigned short Bs[144 * 168];

    const int tid  = threadIdx.x;
    const int wave = tid >> 6, lane = tid & 63;
    const int kg   = lane >> 4, c15 = lane & 15;

    for (int i = tid; i < 12096; i += 256) ((unsigned*)Bs)[i] = 0u;
    __syncthreads();
    for (int idx = tid; idx < 17161; idx += 256) {
        unsigned n = (unsigned)idx / 131u, k = (unsigned)idx - n * 131u;
        Bs[n * 168 + k] = f2bf(w2[idx]);
    }
    __syncthreads();

    const int rwave = blockIdx.x * 256 + wave * 64;

    #pragma unroll 1
    for (int mp = 0; mp < 2; mp++) {
        short8 af[2][5];
        #pragma unroll
        for (int mi = 0; mi < 2; mi++) {
            int arow = rwave + mp * 32 + mi * 16 + c15;
            #pragma unroll
            for (int ks = 0; ks < 5; ks++) {
                short8 res = {0, 0, 0, 0, 0, 0, 0, 0};
                if (ks < 4 || kg < 2) {
                    int p = (ks < 4) ? (ks * 2 + (kg >> 1)) : 8;
                    short8 h8 = *(const short8*)(H + (size_t)p * PLANE_US +
                                                 (size_t)arow * 16 + (kg & 1) * 8);
                    int c0 = ks * 32 + kg * 8;
                    f32x4 scA = *(const f32x4*)(scalep + c0);
                    f32x4 scB = *(const f32x4*)(scalep + c0 + 4);
                    f32x4 shA = *(const f32x4*)(shiftp + c0);
                    f32x4 shB = *(const f32x4*)(shiftp + c0 + 4);
                    #pragma unroll
                    for (int e = 0; e < 8; e++) {
                        float hf = bf2f((unsigned short)h8[e]);
                        float sc = (e < 4) ? scA[e & 3] : scB[e & 3];
                        float sh = (e < 4) ? shA[e & 3] : shB[e & 3];
                        res[e] = (short)f2bf(fmaxf(hf * sc + sh, 0.0f));
                    }
                }
                af[mi][ks] = res;
            }
        }
        #pragma unroll 1
        for (int n = 0; n < 9; n++) {
            int col = n * 16 + c15;
            float bias = (col < 131) ? b2[col] : 0.0f;
            short8 bf[5];
            #pragma unroll
            for (int ks = 0; ks < 5; ks++)
                bf[ks] = *(const short8*)&Bs[(unsigned)(n * 16 + c15) * 168 + ks * 32 + kg * 8];
            f32x4 acc0 = {bias, bias, bias, bias};
            f32x4 acc1 = {bias, bias, bias, bias};
            #pragma unroll
            for (int ks = 0; ks < 5; ks++) {
                acc0 = __builtin_amdgcn_mfma_f32_16x16x32_bf16(af[0][ks], bf[ks], acc0, 0, 0, 0);
                acc1 = __builtin_amdgcn_mfma_f32_16x16x32_bf16(af[1][ks], bf[ks], acc1, 0, 0, 0);
            }
            if (col < 131) {
                #pragma unroll
                for (int r = 0; r < 4; r++) {
                    out[(size_t)(rwave + mp * 32 + kg * 4 + r) * 131 + col]      = acc0[r];
                    out[(size_t)(rwave + mp * 32 + 16 + kg * 4 + r) * 131 + col] = acc1[r];
                }
            }
        }
    }
}

extern "C" void kernel_launch(void* const* d_in, const int* in_sizes, int n_in,
                              void* d_out, int out_size, void* d_ws, size_t ws_size,
                              hipStream_t stream) {
    (void)in_sizes; (void)n_in; (void)out_size; (void)ws_size;
    const float* corner = (const float*)d_in[0];
    const float* normal = (const float*)d_in[1];
    const float* conv_w = (const float*)d_in[3];
    const float* conv_b = (const float*)d_in[4];
    const float* lin3_w = (const float*)d_in[5];
    const float* lin3_b = (const float*)d_in[6];
    const float* lin4_w = (const float*)d_in[7];
    const float* lin4_b = (const float*)d_in[8];
    const float* kern   = (const float*)d_in[9];
    const float* w1     = (const float*)d_in[10];
    const float* b1     = (const float*)d_in[11];
    const float* bn_g   = (const float*)d_in[12];
    const float* bn_b   = (const float*)d_in[13];
    const float* w2     = (const float*)d_in[14];
    const float* b2     = (const float*)d_in[15];

    unsigned short* X  = (unsigned short*)d_out;          // 8 planes, dead before k_B writes
    unsigned short* H  = (unsigned short*)d_ws;           // 9 planes = 75,497,472 B
    float* sums   = (float*)((char*)d_ws + 9 * PLANE_B);  // 64 slots * 288 f32
    float* scalep = sums + 64 * 288;                      // 160 f32
    float* shiftp = scalep + 160;                         // 160 f32
    float* outp   = (float*)d_out;

    hipMemsetAsync(sums, 0, 64 * 288 * sizeof(float), stream);
    k_A1<<<NBLK, 256, 0, stream>>>(corner, normal, conv_w, conv_b, lin3_w, lin3_b,
                                   lin4_w, lin4_b, kern, X);
    k_A2<<<NBLK, 256, 0, stream>>>(X, normal, w1, b1, H, sums);
    k_stats<<<1, 256, 0, stream>>>(sums, bn_g, bn_b, scalep, shiftp);
    k_B<<<NBLK, 256, 0, stream>>>(H, scalep, shiftp, w2, b2, outp);
}

// Round 4
// 315.792 us; speedup vs baseline: 13.9688x; 1.1723x over previous
//
#include <hip/hip_runtime.h>

#define NROWS 262144
#define PLANE_B   8388608ull   // NROWS*32 bytes per 16-col bf16 plane
#define PLANE_US  4194304ull   // ushorts per plane
#define KS 168                 // A/B row stride in ushorts (bank-friendly, 16B-mult)

// ws byte offsets
#define H_B    0ull                          // 9 planes = 75,497,472 B
#define W1P_B  75497472ull                   // 144*168 bf16 = 48384 B
#define W2P_B  75545856ull                   // 48384 B
#define B1P_B  75594240ull                   // 144 f32
#define G4_B   75594816ull                   // 64*4 f32
#define ZT_B   75595840ull                   // 256*4 f32
#define SUMS_B 75599936ull                   // 32 slots * 288 f32 = 36864 B

typedef short  short8 __attribute__((ext_vector_type(8)));
typedef float  f32x4  __attribute__((ext_vector_type(4)));

static __device__ __forceinline__ unsigned short f2bf(float f) {
    unsigned u = __float_as_uint(f);
    u = u + 0x7fffu + ((u >> 16) & 1u);   // RNE
    return (unsigned short)(u >> 16);
}
static __device__ __forceinline__ float bf2f(unsigned short h) {
    return __uint_as_float(((unsigned)h) << 16);
}

// ------------------------------------------------------------------
// k_prep: fold the linear front-end into GEMM-ready tables.
//  blocks 0..143: W1P[j][:] = [W1v@lin4 (64) | W1z (64) | W1n (3) | 0],
//                 W2P[j][:], b1p[j] = b1[j] + W1v@b4
//  block 144: G4[o] = {G0,G1,G2,g0}  (u = m@G + g0)
//  block 145: ZT[pt] = {2kx,2ky,2kz,-|kp|^2}
// ------------------------------------------------------------------
__global__ __launch_bounds__(64) void k_prep(
    const float* __restrict__ conv_w, const float* __restrict__ conv_b,
    const float* __restrict__ lin3_w, const float* __restrict__ lin3_b,
    const float* __restrict__ lin4_w, const float* __restrict__ lin4_b,
    const float* __restrict__ kern,
    const float* __restrict__ w1, const float* __restrict__ b1,
    const float* __restrict__ w2,
    unsigned short* __restrict__ W1P, unsigned short* __restrict__ W2P,
    float* __restrict__ B1P, float* __restrict__ G4, float* __restrict__ ZT)
{
    const int j = blockIdx.x;
    const int l = threadIdx.x;
    if (j < 144) {
        const bool jv = (j < 131);
        float acc = 0.0f;
        if (jv) {
            #pragma unroll 4
            for (int o = 0; o < 64; o++)
                acc += w1[j * 131 + 3 + o] * lin4_w[o * 64 + l];
        }
        W1P[j * KS + l]      = jv ? f2bf(acc) : (unsigned short)0;
        W1P[j * KS + 64 + l] = jv ? f2bf(w1[j * 131 + 67 + l]) : (unsigned short)0;
        if (l < 40) {
            float v = (jv && l < 3) ? w1[j * 131 + l] : 0.0f;
            W1P[j * KS + 128 + l] = f2bf(v);
        }
        W2P[j * KS + l]      = jv ? f2bf(w2[j * 131 + l]) : (unsigned short)0;
        W2P[j * KS + 64 + l] = (jv && (64 + l) < 131) ? f2bf(w2[j * 131 + 64 + l]) : (unsigned short)0;
        if (l < 40) {
            int k2 = 128 + l;
            W2P[j * KS + k2] = (jv && k2 < 131) ? f2bf(w2[j * 131 + k2]) : (unsigned short)0;
        }
        if (l == 0) {
            float bb = 0.0f;
            if (jv) {
                bb = b1[j];
                for (int o = 0; o < 64; o++) bb += w1[j * 131 + 3 + o] * lin4_b[o];
            }
            B1P[j] = bb;
        }
    } else if (j == 144) {
        float g0v = lin3_b[l], ga = 0.0f, gb = 0.0f, gc = 0.0f;
        #pragma unroll 4
        for (int i = 0; i < 32; i++) {
            float wv = lin3_w[l * 32 + i];
            ga  += wv * (conv_w[i * 6 + 0] + conv_w[i * 6 + 3]);
            gb  += wv * (conv_w[i * 6 + 1] + conv_w[i * 6 + 4]);
            gc  += wv * (conv_w[i * 6 + 2] + conv_w[i * 6 + 5]);
            g0v += wv * conv_b[i];
        }
        G4[l * 4 + 0] = ga; G4[l * 4 + 1] = gb; G4[l * 4 + 2] = gc; G4[l * 4 + 3] = g0v;
    } else {
        #pragma unroll
        for (int p = 0; p < 4; p++) {
            int idx = l * 4 + p;
            float kx = kern[idx * 3 + 0], ky = kern[idx * 3 + 1], kz = kern[idx * 3 + 2];
            ZT[idx * 4 + 0] = 2.0f * kx;
            ZT[idx * 4 + 1] = 2.0f * ky;
            ZT[idx * 4 + 2] = 2.0f * kz;
            ZT[idx * 4 + 3] = -(kx * kx + ky * ky + kz * kz);
        }
    }
}

// ------------------------------------------------------------------
// k_F: fused front-end + GEMM1. 128 threads = 2 waves, 128 rows/block.
//  per thread: t[64] = relu(m@G+g0), z[64] RBF -> LDS X row (bf16, stride 168)
//  per wave: H(64x144) = X @ W1P^T + b1p via MFMA; BN stats; H planes out.
// ------------------------------------------------------------------
__global__ __launch_bounds__(128) void k_F(
    const float* __restrict__ corner, const float* __restrict__ normal,
    const unsigned short* __restrict__ W1P, const float* __restrict__ B1P,
    const float* __restrict__ G4, const float* __restrict__ ZT,
    unsigned short* __restrict__ H, float* __restrict__ sums)
{
    __shared__ unsigned short Xs[128 * KS];        // 43008 B
    __shared__ unsigned short mini[2 * 64 * 20];   // 5120 B
    __shared__ float sl[288];

    const int tid  = threadIdx.x;
    const int wave = tid >> 6, lane = tid & 63;
    const int kg   = lane >> 4, c15 = lane & 15;
    const int row  = blockIdx.x * 128 + tid;

    for (int i = tid; i < 288; i += 128) sl[i] = 0.0f;

    // ---- inputs ----
    const float* cp = corner + (size_t)row * 9;
    float c0 = cp[0], c1 = cp[1], c2 = cp[2], c3 = cp[3], c4 = cp[4],
          c5 = cp[5], c6 = cp[6], c7 = cp[7], c8 = cp[8];
    const float n0 = normal[row * 3 + 0];
    const float n1 = normal[row * 3 + 1];
    const float n2 = normal[row * 3 + 2];
    const float m0 = (c0 + c3 + c6) * (1.0f / 3.0f);
    const float m1 = (c1 + c4 + c7) * (1.0f / 3.0f);
    const float m2 = (c2 + c5 + c8) * (1.0f / 3.0f);
    const float nn = n0 * n0 + n1 * n1 + n2 * n2;

    unsigned short* xrow = Xs + tid * KS;

    // ---- t: chunks 0..7 ----
    #pragma unroll
    for (int q = 0; q < 8; q++) {
        short8 pk;
        #pragma unroll
        for (int e = 0; e < 8; e++) {
            int o = q * 8 + e;
            float u = G4[o * 4 + 3] + m0 * G4[o * 4 + 0] + m1 * G4[o * 4 + 1] + m2 * G4[o * 4 + 2];
            pk[e] = (short)f2bf(fmaxf(u, 0.0f));
        }
        *(short8*)(xrow + q * 8) = pk;
    }
    // ---- z: chunks 8..15 ----
    #pragma unroll
    for (int q = 0; q < 8; q++) {
        short8 pk;
        #pragma unroll
        for (int e = 0; e < 8; e++) {
            int mi = q * 8 + e;
            float acc = 0.0f;
            #pragma unroll
            for (int lp = 0; lp < 4; lp++) {
                const float* zt = ZT + (mi * 4 + lp) * 4;
                float w = zt[3] + zt[0] * n0 + zt[1] * n1 + zt[2] * n2 - nn;
                acc += __expf(w);
            }
            pk[e] = (short)f2bf(acc * 0.03125f);
        }
        *(short8*)(xrow + 64 + q * 8) = pk;
    }
    // ---- normal + zero pad: chunks 16..19 ----
    {
        short8 pk = {0, 0, 0, 0, 0, 0, 0, 0};
        pk[0] = (short)f2bf(n0); pk[1] = (short)f2bf(n1); pk[2] = (short)f2bf(n2);
        *(short8*)(xrow + 128) = pk;
        short8 zz = {0, 0, 0, 0, 0, 0, 0, 0};
        *(short8*)(xrow + 136) = zz;
        *(short8*)(xrow + 144) = zz;
        *(short8*)(xrow + 152) = zz;
    }

    __syncthreads();

    // ---- A-fragments resident (own 64 rows) ----
    short8 af[4][5];
    #pragma unroll
    for (int mi = 0; mi < 4; mi++)
        #pragma unroll
        for (int ks = 0; ks < 5; ks++)
            af[mi][ks] = *(const short8*)(Xs + (wave * 64 + mi * 16 + c15) * KS + ks * 32 + kg * 8);

    #pragma unroll 1
    for (int n = 0; n < 9; n++) {
        const int col = n * 16 + c15;
        const float bias = B1P[col];
        short8 bf[5];
        #pragma unroll
        for (int ks = 0; ks < 5; ks++)
            bf[ks] = *(const short8*)(W1P + (size_t)col * KS + ks * 32 + kg * 8);
        float s1 = 0.0f, s2 = 0.0f;
        #pragma unroll
        for (int mi = 0; mi < 4; mi++) {
            f32x4 acc = {bias, bias, bias, bias};
            #pragma unroll
            for (int ks = 0; ks < 5; ks++)
                acc = __builtin_amdgcn_mfma_f32_16x16x32_bf16(af[mi][ks], bf[ks], acc, 0, 0, 0);
            #pragma unroll
            for (int r = 0; r < 4; r++) {
                s1 += acc[r]; s2 += acc[r] * acc[r];
                mini[(wave * 64 + mi * 16 + kg * 4 + r) * 20 + c15] = f2bf(acc[r]);
            }
        }
        s1 += __shfl_xor(s1, 16); s2 += __shfl_xor(s2, 16);
        s1 += __shfl_xor(s1, 32); s2 += __shfl_xor(s2, 32);
        if (lane < 16) { atomicAdd(&sl[col], s1); atomicAdd(&sl[144 + col], s2); }
        asm volatile("s_waitcnt lgkmcnt(0)" ::: "memory");
        __builtin_amdgcn_sched_barrier(0);
        const uint2* q = (const uint2*)(mini + (wave * 64 + lane) * 20);
        uint2 q0 = q[0], q1 = q[1], q2 = q[2], q3 = q[3];
        uint4* dst = (uint4*)((char*)H + (size_t)n * PLANE_B +
                              (size_t)(blockIdx.x * 128 + wave * 64 + lane) * 32);
        dst[0] = make_uint4(q0.x, q0.y, q1.x, q1.y);
        dst[1] = make_uint4(q2.x, q2.y, q3.x, q3.y);
    }

    __syncthreads();
    {
        float* d = sums + (blockIdx.x & 31) * 288;
        for (int i = tid; i < 288; i += 128) atomicAdd(&d[i], sl[i]);
    }
}

// ------------------------------------------------------------------
// k_B: out = relu(scale*H + shift) @ W2P^T + b2 (fp32 direct stores).
//  BN params computed per-block from sums (k_stats folded in).
// ------------------------------------------------------------------
__global__ __launch_bounds__(256) void k_B(
    const unsigned short* __restrict__ H, const unsigned short* __restrict__ W2P,
    const float* __restrict__ sums,
    const float* __restrict__ bn_g, const float* __restrict__ bn_b,
    const float* __restrict__ b2, float* __restrict__ out)
{
    __shared__ unsigned short Bs[144 * KS];
    __shared__ __align__(16) float s_scale[160];
    __shared__ __align__(16) float s_shift[160];

    const int tid  = threadIdx.x;
    // linear weight copy (no conversion)
    {
        const uint4* src = (const uint4*)W2P;
        uint4* dst = (uint4*)Bs;
        #pragma unroll
        for (int i = 0; i < 12; i++) {
            int idx = tid + i * 256;
            if (idx < 3024) dst[idx] = src[idx];
        }
    }
    // BN params (redundant per block, overlaps staging)
    if (tid < 160) {
        float sc = 0.0f, sh = 0.0f;
        if (tid < 131) {
            float s1 = 0.0f, s2 = 0.0f;
            #pragma unroll 4
            for (int s = 0; s < 32; s++) {
                s1 += sums[s * 288 + tid];
                s2 += sums[s * 288 + 144 + tid];
            }
            const float inv = 1.0f / (float)NROWS;
            float mean = s1 * inv;
            float var  = fmaxf(s2 * inv - mean * mean, 0.0f);
            sc = bn_g[tid] * rsqrtf(var + 1e-5f);
            sh = bn_b[tid] - mean * sc;
        }
        s_scale[tid] = sc; s_shift[tid] = sh;
    }
    __syncthreads();

    const int wave = tid >> 6, lane = tid & 63;
    const int kg   = lane >> 4, c15 = lane & 15;
    const int rwave = blockIdx.x * 256 + wave * 64;

    #pragma unroll 1
    for (int mp = 0; mp < 2; mp++) {
        short8 af[2][5];
        #pragma unroll
        for (int mi = 0; mi < 2; mi++) {
            int arow = rwave + mp * 32 + mi * 16 + c15;
            #pragma unroll
            for (int ks = 0; ks < 5; ks++) {
                short8 res = {0, 0, 0, 0, 0, 0, 0, 0};
                if (ks < 4 || kg < 2) {
                    int p = (ks < 4) ? (ks * 2 + (kg >> 1)) : 8;
                    short8 h8 = *(const short8*)(H + (size_t)p * PLANE_US +
                                                 (size_t)arow * 16 + (kg & 1) * 8);
                    int c0 = ks * 32 + kg * 8;
                    #pragma unroll
                    for (int e = 0; e < 8; e++) {
                        float hf = bf2f((unsigned short)h8[e]);
                        res[e] = (short)f2bf(fmaxf(hf * s_scale[c0 + e] + s_shift[c0 + e], 0.0f));
                    }
                }
                af[mi][ks] = res;
            }
        }
        #pragma unroll 1
        for (int n = 0; n < 9; n++) {
            const int col = n * 16 + c15;
            const float bias = (col < 131) ? b2[col] : 0.0f;
            short8 bf[5];
            #pragma unroll
            for (int ks = 0; ks < 5; ks++)
                bf[ks] = *(const short8*)&Bs[(unsigned)col * KS + ks * 32 + kg * 8];
            f32x4 acc0 = {bias, bias, bias, bias};
            f32x4 acc1 = {bias, bias, bias, bias};
            #pragma unroll
            for (int ks = 0; ks < 5; ks++) {
                acc0 = __builtin_amdgcn_mfma_f32_16x16x32_bf16(af[0][ks], bf[ks], acc0, 0, 0, 0);
                acc1 = __builtin_amdgcn_mfma_f32_16x16x32_bf16(af[1][ks], bf[ks], acc1, 0, 0, 0);
            }
            if (col < 131) {
                #pragma unroll
                for (int r = 0; r < 4; r++) {
                    out[(size_t)(rwave + mp * 32 + kg * 4 + r) * 131 + col]      = acc0[r];
                    out[(size_t)(rwave + mp * 32 + 16 + kg * 4 + r) * 131 + col] = acc1[r];
                }
            }
        }
    }
}

extern "C" void kernel_launch(void* const* d_in, const int* in_sizes, int n_in,
                              void* d_out, int out_size, void* d_ws, size_t ws_size,
                              hipStream_t stream) {
    (void)in_sizes; (void)n_in; (void)out_size; (void)ws_size;
    const float* corner = (const float*)d_in[0];
    const float* normal = (const float*)d_in[1];
    const float* conv_w = (const float*)d_in[3];
    const float* conv_b = (const float*)d_in[4];
    const float* lin3_w = (const float*)d_in[5];
    const float* lin3_b = (const float*)d_in[6];
    const float* lin4_w = (const float*)d_in[7];
    const float* lin4_b = (const float*)d_in[8];
    const float* kern   = (const float*)d_in[9];
    const float* w1     = (const float*)d_in[10];
    const float* b1     = (const float*)d_in[11];
    const float* bn_g   = (const float*)d_in[12];
    const float* bn_b   = (const float*)d_in[13];
    const float* w2     = (const float*)d_in[14];
    const float* b2     = (const float*)d_in[15];

    char* wsb = (char*)d_ws;
    unsigned short* Hp  = (unsigned short*)(wsb + H_B);
    unsigned short* W1P = (unsigned short*)(wsb + W1P_B);
    unsigned short* W2P = (unsigned short*)(wsb + W2P_B);
    float* B1P  = (float*)(wsb + B1P_B);
    float* G4   = (float*)(wsb + G4_B);
    float* ZT   = (float*)(wsb + ZT_B);
    float* sums = (float*)(wsb + SUMS_B);
    float* outp = (float*)d_out;

    hipMemsetAsync(sums, 0, 32 * 288 * sizeof(float), stream);
    k_prep<<<146, 64, 0, stream>>>(conv_w, conv_b, lin3_w, lin3_b, lin4_w, lin4_b,
                                   kern, w1, b1, w2, W1P, W2P, B1P, G4, ZT);
    k_F<<<NROWS / 128, 128, 0, stream>>>(corner, normal, W1P, B1P, G4, ZT, Hp, sums);
    k_B<<<NROWS / 256, 256, 0, stream>>>(Hp, W2P, sums, bn_g, bn_b, b2, outp);
}